// Round 14
// baseline (92.067 us; speedup 1.0000x reference)
//
#include <hip/hip_runtime.h>

typedef unsigned int u32;
typedef unsigned short u16;
typedef unsigned char u8;
typedef _Float16 f16;
typedef __attribute__((ext_vector_type(2))) _Float16 f16x2;
typedef __attribute__((ext_vector_type(4))) _Float16 f16x4;
typedef __attribute__((ext_vector_type(8))) _Float16 f16x8;
typedef __attribute__((ext_vector_type(4))) float f32x4;
typedef __attribute__((ext_vector_type(4))) u32 u32x4;

#if __has_builtin(__builtin_amdgcn_mfma_f32_16x16x16f16)
#define USE_K16 1
#else
#define USE_K16 0
#endif

__device__ __forceinline__ float bf16f(u16 v) { u32 x = ((u32)v) << 16; return __builtin_bit_cast(float, x); }
__device__ __forceinline__ u16 f2bf(float f) {  // round-to-nearest-even (proven)
    u32 x = __builtin_bit_cast(u32, f);
    return (u16)((x + 0x7fffu + ((x >> 16) & 1u)) >> 16);
}

// ---------------------------------------------------------------------------
// M[row][col]: folded layer-1 matrix, K=128 row map (VERBATIM r13).
// ---------------------------------------------------------------------------
__device__ float m_val(int row, int col, const float* __restrict__ W,
                       const float* __restrict__ a1) {
    if (row >= 96) {
        int k = row - 96;
        return (k < 25 && col >= 64) ? W[k * 64 + (col - 64)] : 0.f;
    }
    int seg = row >> 5;
    int k = row & 31;
    if (k >= 25) return 0.f;
    int cc = (col < 64) ? col : col - 64;
    int arow = (col < 64) ? cc : 64 + cc;
    float e0 = __expf(a1[arow * 3 + 0]);
    float e1 = __expf(a1[arow * 3 + 1]);
    float e2 = __expf(a1[arow * 3 + 2]);
    float wt = ((seg == 0) ? e0 : (seg == 1) ? e1 : e2) / (e0 + e1 + e2);
    float v = W[k * 64 + cc] * wt * (1.f / 32.f);
    return (col < 64) ? v : -v;
}

// ---------------------------------------------------------------------------
// k_prep_all: MERGED r13 k_prep + k_prepM (one launch instead of two).
//  blocks [0, prepBlocks):  featq[row][col] = u8(round(feat*16)+128), pad 128
//  blocks [prepBlocks, +64): Bpack = M in MFMA B-fragment order (r13 packing)
// ---------------------------------------------------------------------------
__global__ __launch_bounds__(256) void k_prep_all(const float* __restrict__ feat,
                                                  const float* __restrict__ W,
                                                  const float* __restrict__ a1,
                                                  u8* __restrict__ featq,
                                                  f16* __restrict__ Bpack,
                                                  int N, int prepBlocks) {
    if ((int)blockIdx.x >= prepBlocks) {   // ---- prepM part (r13 verbatim math)
        int idx = ((int)blockIdx.x - prepBlocks) * 256 + threadIdx.x;  // 0..16383
#if USE_K16
        int j = idx & 3, l = (idx >> 2) & 63, ks = (idx >> 8) & 7, ct = idx >> 11;
        int row = ks * 16 + ((l >> 4) << 2) + j;
#else
        int j = idx & 7, l = (idx >> 3) & 63, ks = (idx >> 9) & 3, ct = idx >> 11;
        int row = ks * 32 + ((l >> 4) << 3) + j;
#endif
        int col = ct * 16 + (l & 15);
        Bpack[idx] = (f16)m_val(row, col, W, a1);
        return;
    }
    // ---- featq part (r13 verbatim)
    int t = blockIdx.x * 256 + threadIdx.x;
    int row = t >> 5, col = t & 31;
    if (row >= N) return;
    int qv = 128;
    if (col < 25) {
        float f = feat[(size_t)row * 25 + col];
        int qi = __float2int_rn(f * 16.f);
        qi = max(-127, min(127, qi));
        qv = qi + 128;
    }
    featq[(size_t)row * 32 + col] = (u8)qv;
}

// ---------------------------------------------------------------------------
// k_layer1f v6: r13 VERBATIM except the 8 row-gather loads use
// __builtin_nontemporal_load (L1-bypass experiment; featq L1 hit ~2%).
// ---------------------------------------------------------------------------
__global__ __launch_bounds__(256) void k_layer1f(const float* __restrict__ feat,
                                                 const u8* __restrict__ featq,
                                                 const int* __restrict__ adj,
                                                 const f16* __restrict__ Bpack,
                                                 u16* __restrict__ w1, int N) {
    __shared__ f16 x[32][104];       // cols 0..95 neighbor sums; stride 104
    __shared__ int s_idx[32][100];   // 96 used; stride 100 -> conflict-free
    int tid = threadIdx.x;
    int i0 = blockIdx.x * 32;

    {   // stage indices: thread t -> node t>>3, l8 = t&7; 12 loads each
        int node = tid >> 3, l8 = tid & 7;
        int nsafe = (i0 + node < N) ? (i0 + node) : 0;
#pragma unroll
        for (int j = 0; j < 12; ++j) {
            int jj = l8 + j * 8;          // 0..95
            int rr = jj >> 5, kk = jj & 31;
            s_idx[node][jj] = __builtin_nontemporal_load(adj + ((size_t)rr * N + nsafe) * 32 + kk);
        }
    }
    __syncthreads();

    int w = tid >> 6;
    int l = tid & 63;
    int q = l >> 4;         // neighbor sub-offset 0..3
    int m = (l >> 1) & 7;   // node within wave
    int e = l & 1;          // 16B half of the 32B row
    int nodeLocal = w * 8 + m;
    const u32x4* fq = (const u32x4*)featq;   // 2 u32x4 per 32B row

#pragma unroll
    for (int r = 0; r < 3; ++r) {
        int idxv[8];
#pragma unroll
        for (int kq = 0; kq < 8; ++kq)
            idxv[kq] = s_idx[nodeLocal][r * 32 + kq * 4 + q];

        u32x4 stA[4], stB[4];
#pragma unroll
        for (int j = 0; j < 4; ++j)
            stA[j] = __builtin_nontemporal_load(fq + (size_t)idxv[j] * 2 + e);
#pragma unroll
        for (int j = 0; j < 4; ++j)
            stB[j] = __builtin_nontemporal_load(fq + (size_t)idxv[4 + j] * 2 + e);

        u32 ea[4] = {0u, 0u, 0u, 0u}, oa[4] = {0u, 0u, 0u, 0u};
#pragma unroll
        for (int j = 0; j < 4; ++j) {
            u32x4 v = stA[j];
#pragma unroll
            for (int c = 0; c < 4; ++c) {
                ea[c] += (v[c] & 0x00FF00FFu);
                oa[c] += ((v[c] >> 8) & 0x00FF00FFu);
            }
        }
#pragma unroll
        for (int j = 0; j < 4; ++j) {
            u32x4 v = stB[j];
#pragma unroll
            for (int c = 0; c < 4; ++c) {
                ea[c] += (v[c] & 0x00FF00FFu);
                oa[c] += ((v[c] >> 8) & 0x00FF00FFu);
            }
        }
#pragma unroll
        for (int c = 0; c < 4; ++c) {   // reduce over q: PROVEN masks 16,32
            ea[c] += (u32)__shfl_xor((int)ea[c], 16, 64);
            ea[c] += (u32)__shfl_xor((int)ea[c], 32, 64);
            oa[c] += (u32)__shfl_xor((int)oa[c], 16, 64);
            oa[c] += (u32)__shfl_xor((int)oa[c], 32, 64);
        }
        if (q == 0) {   // 16 lanes (e,m) write 16 cols = 2x16B each
            f16x8 o0, o1;
#pragma unroll
            for (int j = 0; j < 4; ++j) {
                f16 v0 = (f16)(((float)(int)(ea[j] & 0xFFFFu) - 4096.f) * 0.0625f);
                f16 v1 = (f16)(((float)(int)(oa[j] & 0xFFFFu) - 4096.f) * 0.0625f);
                f16 v2 = (f16)(((float)(int)(ea[j] >> 16) - 4096.f) * 0.0625f);
                f16 v3 = (f16)(((float)(int)(oa[j] >> 16) - 4096.f) * 0.0625f);
                if (j < 2) { o0[j * 4 + 0] = v0; o0[j * 4 + 1] = v1; o0[j * 4 + 2] = v2; o0[j * 4 + 3] = v3; }
                else { o1[(j - 2) * 4 + 0] = v0; o1[(j - 2) * 4 + 1] = v1; o1[(j - 2) * 4 + 2] = v2; o1[(j - 2) * 4 + 3] = v3; }
            }
            *(f16x8*)&x[nodeLocal][r * 32 + e * 16] = o0;
            *(f16x8*)&x[nodeLocal][r * 32 + e * 16 + 8] = o1;
        }
    }
    __syncthreads();

    // ---- MFMA phase (r13 VERBATIM) ----
    int tile = w >> 1;
    int nodeA = tile * 16 + (l & 15);
    int nsA = (i0 + nodeA < N) ? (i0 + nodeA) : 0;
    const float* fr = feat + (size_t)nsA * 25;
#if USE_K16
    f16x4 a[8];
    {
        const f16* xrow = &x[nodeA][(l >> 4) << 2];
#pragma unroll
        for (int ks = 0; ks < 6; ++ks) a[ks] = *(const f16x4*)(xrow + ks * 16);
#pragma unroll
        for (int ks = 6; ks < 8; ++ks)
#pragma unroll
            for (int j = 0; j < 4; ++j) {
                int k = (ks - 6) * 16 + ((l >> 4) << 2) + j;   // self col 0..31
                a[ks][j] = (k < 25) ? (f16)fr[k] : (f16)0.f;
            }
    }
#pragma unroll
    for (int ctt = 0; ctt < 4; ++ctt) {
        int ct = (w & 1) * 4 + ctt;
        f32x4 d = {0.f, 0.f, 0.f, 0.f};
        const f16* bp = Bpack + ((size_t)(ct * 8) * 64 + l) * 4;
#pragma unroll
        for (int ks = 0; ks < 8; ++ks) {
            f16x4 b = *(const f16x4*)(bp + ks * 256);
            d = __builtin_amdgcn_mfma_f32_16x16x16f16(a[ks], b, d, 0, 0, 0);
        }
#pragma unroll
        for (int reg = 0; reg < 4; ++reg) {
            int n2 = i0 + tile * 16 + ((l >> 4) << 2) + reg;
            if (n2 < N) w1[(size_t)n2 * 128 + ct * 16 + (l & 15)] = f2bf(d[reg]);
        }
    }
#else
    f16x8 a[4];
    {
        const f16* xrow = &x[nodeA][(l >> 4) << 3];
#pragma unroll
        for (int ks = 0; ks < 3; ++ks) a[ks] = *(const f16x8*)(xrow + ks * 32);
#pragma unroll
        for (int j = 0; j < 8; ++j) {
            int k = ((l >> 4) << 3) + j;                        // self col 0..31
            a[3][j] = (k < 25) ? (f16)fr[k] : (f16)0.f;
        }
    }
#pragma unroll
    for (int ctt = 0; ctt < 4; ++ctt) {
        int ct = (w & 1) * 4 + ctt;
        f32x4 d = {0.f, 0.f, 0.f, 0.f};
        const f16* bp = Bpack + ((size_t)(ct * 4) * 64 + l) * 8;
#pragma unroll
        for (int ks = 0; ks < 4; ++ks) {
            f16x8 b = *(const f16x8*)(bp + ks * 512);
            d = __builtin_amdgcn_mfma_f32_16x16x32_f16(a[ks], b, d, 0, 0, 0);
        }
#pragma unroll
        for (int reg = 0; reg < 4; ++reg) {
            int n2 = i0 + tile * 16 + ((l >> 4) << 2) + reg;
            if (n2 < N) w1[(size_t)n2 * 128 + ct * 16 + (l & 15)] = f2bf(d[reg]);
        }
    }
#endif
}

// ---------------------------------------------------------------------------
// k_layer2: round-13 VERBATIM (passed).
// ---------------------------------------------------------------------------
__global__ __launch_bounds__(128) void k_layer2(const float* __restrict__ feat,
                                                const float* __restrict__ Wmlp,
                                                const u16* __restrict__ w1h,
                                                const float* __restrict__ alpha2,
                                                const float* __restrict__ lw,
                                                const float* __restrict__ prior,
                                                const int* __restrict__ adj,
                                                const int* __restrict__ nodes,
                                                float* __restrict__ out, int N) {
    __shared__ int s_idx[96];
    __shared__ float s_red[4];
    int b = blockIdx.x;
    int i = nodes[b];
    int t = threadIdx.x;

    if (t < 96) {
        int r = t >> 5, k = t & 31;
        s_idx[t] = adj[((size_t)r * N + i) * 32 + k];
    }
    __syncthreads();

    float mean[3];
#pragma unroll
    for (int r = 0; r < 3; ++r) {
        float acc = 0.f;
#pragma unroll
        for (int k = 0; k < 32; ++k)
            acc += bf16f(w1h[(size_t)s_idx[r * 32 + k] * 128 + t]);  // coalesced
        mean[r] = acc * (1.f / 32.f);
    }

    float et[3], eb[3], st = 0.f, sb = 0.f;
#pragma unroll
    for (int r = 0; r < 3; ++r) {
        et[r] = __expf(alpha2[t * 3 + r]);         st += et[r];
        eb[r] = __expf(alpha2[(128 + t) * 3 + r]); sb += eb[r];
    }
    float t2 = 0.f, wb = 0.f;
#pragma unroll
    for (int r = 0; r < 3; ++r) { t2 += et[r] * mean[r]; wb += eb[r] * mean[r]; }
    t2 /= st;
    wb /= sb;

    float t1 = bf16f(w1h[(size_t)i * 128 + t]);
    float t3 = t1 - wb;

    float p0 = t1 * lw[(64 + t) * 2 + 0] + t2 * lw[(192 + t) * 2 + 0] + t3 * lw[(320 + t) * 2 + 0];
    float p1 = t1 * lw[(64 + t) * 2 + 1] + t2 * lw[(192 + t) * 2 + 1] + t3 * lw[(320 + t) * 2 + 1];
    if (t < 64) {
        float t0 = 0.f;
#pragma unroll
        for (int k = 0; k < 25; ++k) t0 += feat[(size_t)i * 25 + k] * Wmlp[k * 64 + t];
        p0 += t0 * lw[t * 2 + 0];
        p1 += t0 * lw[t * 2 + 1];
    }

#pragma unroll
    for (int off = 32; off > 0; off >>= 1) {
        p0 += __shfl_down(p0, off, 64);
        p1 += __shfl_down(p1, off, 64);
    }
    int wv = t >> 6, lane = t & 63;
    if (lane == 0) { s_red[wv * 2 + 0] = p0; s_red[wv * 2 + 1] = p1; }
    __syncthreads();
    if (t == 0) {
        out[b * 2 + 0] = s_red[0] + s_red[2] + __logf(prior[0]);
        out[b * 2 + 1] = s_red[1] + s_red[3] + __logf(prior[1]);
    }
}

extern "C" void kernel_launch(void* const* d_in, const int* in_sizes, int n_in,
                              void* d_out, int out_size, void* d_ws, size_t ws_size,
                              hipStream_t stream) {
    const float* feat   = (const float*)d_in[0];  // [N,25]
    const float* Wmlp   = (const float*)d_in[1];  // [25,64]
    const float* alpha1 = (const float*)d_in[2];  // [128,3]
    const float* alpha2 = (const float*)d_in[3];  // [256,3]
    const float* lw     = (const float*)d_in[4];  // [448,2]
    const float* prior  = (const float*)d_in[5];  // [2]
    const int*   adj    = (const int*)d_in[6];    // [3,N,32]
    const int*   nodes  = (const int*)d_in[7];    // [B]
    float* out = (float*)d_out;

    int N = in_sizes[0] / 25;   // 50000
    int B = in_sizes[7];        // 1024

    // ws: featq [N][32] u8 (1.6MB) | w1 [N][128] u16 (12.8MB) | Bpack 32KB
    // total ~14.4MB (< 28.8MB proven-safe). NO aliasing.
    char* base = (char*)d_ws;
    u8*  featq = (u8*)base;
    u16* w1    = (u16*)(base + (size_t)N * 32);
    f16* Bpack = (f16*)(base + (size_t)N * 32 + (size_t)N * 128 * 2);

    int prepBlocks = (N * 32 + 255) / 256;   // 6250
    k_prep_all<<<prepBlocks + 64, 256, 0, stream>>>(feat, Wmlp, alpha1, featq, Bpack, N, prepBlocks);
    k_layer1f <<<(N + 31) / 32,   256, 0, stream>>>(feat, featq, adj, Bpack, w1, N);
    k_layer2  <<<B,               128, 0, stream>>>(feat, Wmlp, w1, alpha2, lw, prior, adj, nodes, out, N);
}

// Round 15
// 54.283 us; speedup vs baseline: 1.6961x; 1.6961x over previous
//
#include <hip/hip_runtime.h>

typedef unsigned int u32;
typedef unsigned short u16;
typedef unsigned char u8;
typedef _Float16 f16;
typedef __attribute__((ext_vector_type(2))) _Float16 f16x2;
typedef __attribute__((ext_vector_type(4))) _Float16 f16x4;
typedef __attribute__((ext_vector_type(8))) _Float16 f16x8;
typedef __attribute__((ext_vector_type(4))) float f32x4;
typedef __attribute__((ext_vector_type(4))) u32 u32x4;

#if __has_builtin(__builtin_amdgcn_mfma_f32_16x16x16f16)
#define USE_K16 1
#else
#define USE_K16 0
#endif

__device__ __forceinline__ float bf16f(u16 v) { u32 x = ((u32)v) << 16; return __builtin_bit_cast(float, x); }
__device__ __forceinline__ u16 f2bf(float f) {  // round-to-nearest-even (proven)
    u32 x = __builtin_bit_cast(u32, f);
    return (u16)((x + 0x7fffu + ((x >> 16) & 1u)) >> 16);
}

// ---------------------------------------------------------------------------
// M[row][col]: folded layer-1 matrix, K=128 row map (VERBATIM r13/r14).
// ---------------------------------------------------------------------------
__device__ float m_val(int row, int col, const float* __restrict__ W,
                       const float* __restrict__ a1) {
    if (row >= 96) {
        int k = row - 96;
        return (k < 25 && col >= 64) ? W[k * 64 + (col - 64)] : 0.f;
    }
    int seg = row >> 5;
    int k = row & 31;
    if (k >= 25) return 0.f;
    int cc = (col < 64) ? col : col - 64;
    int arow = (col < 64) ? cc : 64 + cc;
    float e0 = __expf(a1[arow * 3 + 0]);
    float e1 = __expf(a1[arow * 3 + 1]);
    float e2 = __expf(a1[arow * 3 + 2]);
    float wt = ((seg == 0) ? e0 : (seg == 1) ? e1 : e2) / (e0 + e1 + e2);
    float v = W[k * 64 + cc] * wt * (1.f / 32.f);
    return (col < 64) ? v : -v;
}

// ---------------------------------------------------------------------------
// k_prep_all: MERGED prep (r14-proven). featq quantize + Bpack pack.
// ---------------------------------------------------------------------------
__global__ __launch_bounds__(256) void k_prep_all(const float* __restrict__ feat,
                                                  const float* __restrict__ W,
                                                  const float* __restrict__ a1,
                                                  u8* __restrict__ featq,
                                                  f16* __restrict__ Bpack,
                                                  int N, int prepBlocks) {
    if ((int)blockIdx.x >= prepBlocks) {   // ---- prepM part (r13 verbatim math)
        int idx = ((int)blockIdx.x - prepBlocks) * 256 + threadIdx.x;  // 0..16383
#if USE_K16
        int j = idx & 3, l = (idx >> 2) & 63, ks = (idx >> 8) & 7, ct = idx >> 11;
        int row = ks * 16 + ((l >> 4) << 2) + j;
#else
        int j = idx & 7, l = (idx >> 3) & 63, ks = (idx >> 9) & 3, ct = idx >> 11;
        int row = ks * 32 + ((l >> 4) << 3) + j;
#endif
        int col = ct * 16 + (l & 15);
        Bpack[idx] = (f16)m_val(row, col, W, a1);
        return;
    }
    // ---- featq part (r13 verbatim)
    int t = blockIdx.x * 256 + threadIdx.x;
    int row = t >> 5, col = t & 31;
    if (row >= N) return;
    int qv = 128;
    if (col < 25) {
        float f = feat[(size_t)row * 25 + col];
        int qi = __float2int_rn(f * 16.f);
        qi = max(-127, min(127, qi));
        qv = qi + 128;
    }
    featq[(size_t)row * 32 + col] = (u8)qv;
}

// Consume one relation's 8 staged row-halves: exact-integer packed accumulate
// (r13-verbatim math), reduce over q (PROVEN masks 16/32), write x cols.
#define CONSUME_REL(ST, RIDX)                                                   \
    {                                                                           \
        u32 ea[4] = {0u, 0u, 0u, 0u}, oa[4] = {0u, 0u, 0u, 0u};                 \
        _Pragma("unroll")                                                       \
        for (int j = 0; j < 8; ++j) {                                           \
            u32x4 v = ST[j];                                                    \
            _Pragma("unroll")                                                   \
            for (int c = 0; c < 4; ++c) {                                       \
                ea[c] += (v[c] & 0x00FF00FFu);                                  \
                oa[c] += ((v[c] >> 8) & 0x00FF00FFu);                           \
            }                                                                   \
        }                                                                       \
        _Pragma("unroll")                                                       \
        for (int c = 0; c < 4; ++c) {                                           \
            ea[c] += (u32)__shfl_xor((int)ea[c], 16, 64);                       \
            ea[c] += (u32)__shfl_xor((int)ea[c], 32, 64);                       \
            oa[c] += (u32)__shfl_xor((int)oa[c], 16, 64);                       \
            oa[c] += (u32)__shfl_xor((int)oa[c], 32, 64);                       \
        }                                                                       \
        if (q == 0) {                                                           \
            f16x8 o0, o1;                                                       \
            _Pragma("unroll")                                                   \
            for (int j = 0; j < 4; ++j) {                                       \
                f16 v0 = (f16)(((float)(int)(ea[j] & 0xFFFFu) - 4096.f) * 0.0625f); \
                f16 v1 = (f16)(((float)(int)(oa[j] & 0xFFFFu) - 4096.f) * 0.0625f); \
                f16 v2 = (f16)(((float)(int)(ea[j] >> 16) - 4096.f) * 0.0625f); \
                f16 v3 = (f16)(((float)(int)(oa[j] >> 16) - 4096.f) * 0.0625f); \
                if (j < 2) { o0[j * 4 + 0] = v0; o0[j * 4 + 1] = v1; o0[j * 4 + 2] = v2; o0[j * 4 + 3] = v3; } \
                else { o1[(j - 2) * 4 + 0] = v0; o1[(j - 2) * 4 + 1] = v1; o1[(j - 2) * 4 + 2] = v2; o1[(j - 2) * 4 + 3] = v3; } \
            }                                                                   \
            *(f16x8*)&x[nodeLocal][(RIDX) * 32 + e * 16] = o0;                  \
            *(f16x8*)&x[nodeLocal][(RIDX) * 32 + e * 16 + 8] = o1;              \
        }                                                                       \
    }

// ---------------------------------------------------------------------------
// k_layer1f v7: r13 v5 structure (PLAIN cached loads — NT revert), plus a
// 2-relation-deep manual pipeline: issue rel0+rel1 (16 loads in flight),
// consume rel0 while rel1 flies, re-issue rel2 into rel0's staging, consume
// rel1, consume rel2. __launch_bounds__(256,4) allows up to 128 VGPR so the
// compiler keeps the 64-VGPR staging without serializing (r11 lesson: the
// cliff at 64 was binding only because default bounds requested 8 waves/EU).
// ---------------------------------------------------------------------------
__global__ __launch_bounds__(256, 4) void k_layer1f(const float* __restrict__ feat,
                                                    const u8* __restrict__ featq,
                                                    const int* __restrict__ adj,
                                                    const f16* __restrict__ Bpack,
                                                    u16* __restrict__ w1, int N) {
    __shared__ f16 x[32][104];       // cols 0..95 neighbor sums; stride 104
    __shared__ int s_idx[32][100];   // 96 used; stride 100 -> conflict-free
    int tid = threadIdx.x;
    int i0 = blockIdx.x * 32;

    {   // stage indices: thread t -> node t>>3, l8 = t&7; 12 loads each (NT ok: streamed)
        int node = tid >> 3, l8 = tid & 7;
        int nsafe = (i0 + node < N) ? (i0 + node) : 0;
#pragma unroll
        for (int j = 0; j < 12; ++j) {
            int jj = l8 + j * 8;          // 0..95
            int rr = jj >> 5, kk = jj & 31;
            s_idx[node][jj] = __builtin_nontemporal_load(adj + ((size_t)rr * N + nsafe) * 32 + kk);
        }
    }
    __syncthreads();

    int w = tid >> 6;
    int l = tid & 63;
    int q = l >> 4;         // neighbor sub-offset 0..3
    int m = (l >> 1) & 7;   // node within wave
    int e = l & 1;          // 16B half of the 32B row
    int nodeLocal = w * 8 + m;
    const u32x4* fq = (const u32x4*)featq;   // 2 u32x4 per 32B row

    // preload ALL 24 neighbor indices (independent, conflict-free ds_reads)
    int idxv[24];
#pragma unroll
    for (int r = 0; r < 3; ++r)
#pragma unroll
        for (int kq = 0; kq < 8; ++kq)
            idxv[r * 8 + kq] = s_idx[nodeLocal][r * 32 + kq * 4 + q];

    u32x4 st0[8], st1[8];
    // issue rel0 and rel1 (16 loads in flight; PLAIN cached loads)
#pragma unroll
    for (int j = 0; j < 8; ++j)
        st0[j] = *(const u32x4*)(fq + (size_t)idxv[j] * 2 + e);
#pragma unroll
    for (int j = 0; j < 8; ++j)
        st1[j] = *(const u32x4*)(fq + (size_t)idxv[8 + j] * 2 + e);

    CONSUME_REL(st0, 0)             // waits only on st0; st1 stays in flight
#pragma unroll
    for (int j = 0; j < 8; ++j)     // re-issue rel2 into st0's registers
        st0[j] = *(const u32x4*)(fq + (size_t)idxv[16 + j] * 2 + e);
    CONSUME_REL(st1, 1)
    CONSUME_REL(st0, 2)
    __syncthreads();

    // ---- MFMA phase (r13 VERBATIM) ----
    int tile = w >> 1;
    int nodeA = tile * 16 + (l & 15);
    int nsA = (i0 + nodeA < N) ? (i0 + nodeA) : 0;
    const float* fr = feat + (size_t)nsA * 25;
#if USE_K16
    f16x4 a[8];
    {
        const f16* xrow = &x[nodeA][(l >> 4) << 2];
#pragma unroll
        for (int ks = 0; ks < 6; ++ks) a[ks] = *(const f16x4*)(xrow + ks * 16);
#pragma unroll
        for (int ks = 6; ks < 8; ++ks)
#pragma unroll
            for (int j = 0; j < 4; ++j) {
                int k = (ks - 6) * 16 + ((l >> 4) << 2) + j;   // self col 0..31
                a[ks][j] = (k < 25) ? (f16)fr[k] : (f16)0.f;
            }
    }
#pragma unroll
    for (int ctt = 0; ctt < 4; ++ctt) {
        int ct = (w & 1) * 4 + ctt;
        f32x4 d = {0.f, 0.f, 0.f, 0.f};
        const f16* bp = Bpack + ((size_t)(ct * 8) * 64 + l) * 4;
#pragma unroll
        for (int ks = 0; ks < 8; ++ks) {
            f16x4 b = *(const f16x4*)(bp + ks * 256);
            d = __builtin_amdgcn_mfma_f32_16x16x16f16(a[ks], b, d, 0, 0, 0);
        }
#pragma unroll
        for (int reg = 0; reg < 4; ++reg) {
            int n2 = i0 + tile * 16 + ((l >> 4) << 2) + reg;
            if (n2 < N) w1[(size_t)n2 * 128 + ct * 16 + (l & 15)] = f2bf(d[reg]);
        }
    }
#else
    f16x8 a[4];
    {
        const f16* xrow = &x[nodeA][(l >> 4) << 3];
#pragma unroll
        for (int ks = 0; ks < 3; ++ks) a[ks] = *(const f16x8*)(xrow + ks * 32);
#pragma unroll
        for (int j = 0; j < 8; ++j) {
            int k = ((l >> 4) << 3) + j;                        // self col 0..31
            a[3][j] = (k < 25) ? (f16)fr[k] : (f16)0.f;
        }
    }
#pragma unroll
    for (int ctt = 0; ctt < 4; ++ctt) {
        int ct = (w & 1) * 4 + ctt;
        f32x4 d = {0.f, 0.f, 0.f, 0.f};
        const f16* bp = Bpack + ((size_t)(ct * 4) * 64 + l) * 8;
#pragma unroll
        for (int ks = 0; ks < 4; ++ks) {
            f16x8 b = *(const f16x8*)(bp + ks * 512);
            d = __builtin_amdgcn_mfma_f32_16x16x32_f16(a[ks], b, d, 0, 0, 0);
        }
#pragma unroll
        for (int reg = 0; reg < 4; ++reg) {
            int n2 = i0 + tile * 16 + ((l >> 4) << 2) + reg;
            if (n2 < N) w1[(size_t)n2 * 128 + ct * 16 + (l & 15)] = f2bf(d[reg]);
        }
    }
#endif
}

// ---------------------------------------------------------------------------
// k_layer2: round-14 VERBATIM (passed).
// ---------------------------------------------------------------------------
__global__ __launch_bounds__(128) void k_layer2(const float* __restrict__ feat,
                                                const float* __restrict__ Wmlp,
                                                const u16* __restrict__ w1h,
                                                const float* __restrict__ alpha2,
                                                const float* __restrict__ lw,
                                                const float* __restrict__ prior,
                                                const int* __restrict__ adj,
                                                const int* __restrict__ nodes,
                                                float* __restrict__ out, int N) {
    __shared__ int s_idx[96];
    __shared__ float s_red[4];
    int b = blockIdx.x;
    int i = nodes[b];
    int t = threadIdx.x;

    if (t < 96) {
        int r = t >> 5, k = t & 31;
        s_idx[t] = adj[((size_t)r * N + i) * 32 + k];
    }
    __syncthreads();

    float mean[3];
#pragma unroll
    for (int r = 0; r < 3; ++r) {
        float acc = 0.f;
#pragma unroll
        for (int k = 0; k < 32; ++k)
            acc += bf16f(w1h[(size_t)s_idx[r * 32 + k] * 128 + t]);  // coalesced
        mean[r] = acc * (1.f / 32.f);
    }

    float et[3], eb[3], st = 0.f, sb = 0.f;
#pragma unroll
    for (int r = 0; r < 3; ++r) {
        et[r] = __expf(alpha2[t * 3 + r]);         st += et[r];
        eb[r] = __expf(alpha2[(128 + t) * 3 + r]); sb += eb[r];
    }
    float t2 = 0.f, wb = 0.f;
#pragma unroll
    for (int r = 0; r < 3; ++r) { t2 += et[r] * mean[r]; wb += eb[r] * mean[r]; }
    t2 /= st;
    wb /= sb;

    float t1 = bf16f(w1h[(size_t)i * 128 + t]);
    float t3 = t1 - wb;

    float p0 = t1 * lw[(64 + t) * 2 + 0] + t2 * lw[(192 + t) * 2 + 0] + t3 * lw[(320 + t) * 2 + 0];
    float p1 = t1 * lw[(64 + t) * 2 + 1] + t2 * lw[(192 + t) * 2 + 1] + t3 * lw[(320 + t) * 2 + 1];
    if (t < 64) {
        float t0 = 0.f;
#pragma unroll
        for (int k = 0; k < 25; ++k) t0 += feat[(size_t)i * 25 + k] * Wmlp[k * 64 + t];
        p0 += t0 * lw[t * 2 + 0];
        p1 += t0 * lw[t * 2 + 1];
    }

#pragma unroll
    for (int off = 32; off > 0; off >>= 1) {
        p0 += __shfl_down(p0, off, 64);
        p1 += __shfl_down(p1, off, 64);
    }
    int wv = t >> 6, lane = t & 63;
    if (lane == 0) { s_red[wv * 2 + 0] = p0; s_red[wv * 2 + 1] = p1; }
    __syncthreads();
    if (t == 0) {
        out[b * 2 + 0] = s_red[0] + s_red[2] + __logf(prior[0]);
        out[b * 2 + 1] = s_red[1] + s_red[3] + __logf(prior[1]);
    }
}

extern "C" void kernel_launch(void* const* d_in, const int* in_sizes, int n_in,
                              void* d_out, int out_size, void* d_ws, size_t ws_size,
                              hipStream_t stream) {
    const float* feat   = (const float*)d_in[0];  // [N,25]
    const float* Wmlp   = (const float*)d_in[1];  // [25,64]
    const float* alpha1 = (const float*)d_in[2];  // [128,3]
    const float* alpha2 = (const float*)d_in[3];  // [256,3]
    const float* lw     = (const float*)d_in[4];  // [448,2]
    const float* prior  = (const float*)d_in[5];  // [2]
    const int*   adj    = (const int*)d_in[6];    // [3,N,32]
    const int*   nodes  = (const int*)d_in[7];    // [B]
    float* out = (float*)d_out;

    int N = in_sizes[0] / 25;   // 50000
    int B = in_sizes[7];        // 1024

    // ws: featq [N][32] u8 (1.6MB) | w1 [N][128] u16 (12.8MB) | Bpack 32KB
    // total ~14.4MB (< 28.8MB proven-safe). NO aliasing.
    char* base = (char*)d_ws;
    u8*  featq = (u8*)base;
    u16* w1    = (u16*)(base + (size_t)N * 32);
    f16* Bpack = (f16*)(base + (size_t)N * 32 + (size_t)N * 128 * 2);

    int prepBlocks = (N * 32 + 255) / 256;   // 6250
    k_prep_all<<<prepBlocks + 64, 256, 0, stream>>>(feat, Wmlp, alpha1, featq, Bpack, N, prepBlocks);
    k_layer1f <<<(N + 31) / 32,   256, 0, stream>>>(feat, featq, adj, Bpack, w1, N);
    k_layer2  <<<B,               128, 0, stream>>>(feat, Wmlp, w1, alpha2, lw, prior, adj, nodes, out, N);
}